// Round 9
// baseline (138.489 us; speedup 1.0000x reference)
//
#include <hip/hip_runtime.h>
#include <hip/hip_bf16.h>

#define T_LEN 2048
#define BSZ 4
#define EMB 256
#define HDIM 32
#define QSCALE 0.17677669529663687f
#define LOG2E 1.4426950408889634f

using bf16x8 = __attribute__((ext_vector_type(8))) short;
using bf16x4 = __attribute__((ext_vector_type(4))) short;
using f32x4 = __attribute__((ext_vector_type(4))) float;

static __device__ __forceinline__ unsigned fasu(float f) {
  union { float f; unsigned u; } c; c.f = f; return c.u;
}
// pack two floats to packed bf16 pair (round-half-up) in ONE v_perm + 2 adds
static __device__ __forceinline__ unsigned pack2r(float lo, float hi) {
  return __builtin_amdgcn_perm(fasu(hi) + 0x8000u, fasu(lo) + 0x8000u, 0x07060302u);
}
static __device__ __forceinline__ unsigned short bfr(float x) {
  return (unsigned short)((fasu(x) + 0x8000u) >> 16);
}
// build a bf16x8 MFMA fragment from 8 consecutive f32 (two float4 loads)
static __device__ __forceinline__ bf16x8 pack8(const float* __restrict__ p) {
  float4 w0 = ((const float4*)p)[0], w1 = ((const float4*)p)[1];
  union { unsigned u[4]; bf16x8 v; } f;
  f.u[0] = pack2r(w0.x, w0.y);
  f.u[1] = pack2r(w0.z, w0.w);
  f.u[2] = pack2r(w1.x, w1.y);
  f.u[3] = pack2r(w1.z, w1.w);
  return f.v;
}

// ---- cooperative W-tile stage: 64 rows x 256 k of f32 W -> swizzled bf16 LDS ----
// 256-thread version: thread t: row r=t>>2, q4=t&3 covers k = q4*8 + c*32.
// chunk (16B units along k) = c*4+q4; stored at chunk^(r&7) -> 2-way max bank
// pattern on write AND on the hot-loop ds_read_b128 (free, m136).
static __device__ __forceinline__ void stage_w(unsigned short* __restrict__ lds,
                                               const float* __restrict__ W,
                                               int n0, float wscale, int tid) {
  const int r = tid >> 2, q4 = tid & 3;
  const float* wr = W + (n0 + r) * EMB + q4 * 8;
#pragma unroll
  for (int c = 0; c < 8; ++c) {
    float4 f0 = ((const float4*)(wr + c * 32))[0];
    float4 f1 = ((const float4*)(wr + c * 32))[1];
    union { unsigned u[4]; uint4 v; } pk;
    pk.u[0] = pack2r(f0.x * wscale, f0.y * wscale);
    pk.u[1] = pack2r(f0.z * wscale, f0.w * wscale);
    pk.u[2] = pack2r(f1.x * wscale, f1.y * wscale);
    pk.u[3] = pack2r(f1.z * wscale, f1.w * wscale);
    const int chunk = c * 4 + q4;
    *(uint4*)&lds[r * 256 + ((chunk ^ (r & 7)) << 3)] = pk.v;
  }
}
// 512-thread version: row r=t>>3, col-eighth e=t&7 covers k = e*8 + c*64;
// chunk = e + c*8; same swizzle.
static __device__ __forceinline__ void stage_w512(unsigned short* __restrict__ lds,
                                                  const float* __restrict__ W,
                                                  int n0, int tid) {
  const int r = tid >> 3, e = tid & 7;
  const float* wr = W + (n0 + r) * EMB + e * 8;
#pragma unroll
  for (int c = 0; c < 4; ++c) {
    float4 f0 = ((const float4*)(wr + c * 64))[0];
    float4 f1 = ((const float4*)(wr + c * 64))[1];
    union { unsigned u[4]; uint4 v; } pk;
    pk.u[0] = pack2r(f0.x, f0.y);
    pk.u[1] = pack2r(f0.z, f0.w);
    pk.u[2] = pack2r(f1.x, f1.y);
    pk.u[3] = pack2r(f1.z, f1.w);
    const int chunk = e + c * 8;
    *(uint4*)&lds[r * 256 + ((chunk ^ (r & 7)) << 3)] = pk.v;
  }
}
// swizzled fragment read: row, k0 (multiple of 32), quad
static __device__ __forceinline__ bf16x8 read_w(const unsigned short* __restrict__ lds,
                                                int row, int k0, int quad) {
  const int chunk = (k0 >> 3) + quad;
  return *(const bf16x8*)&lds[row * 256 + ((chunk ^ (row & 7)) << 3)];
}

// fused QKV projection: z=0 -> qh [bh][t][32], z=1 -> kh, z=2 -> vt [bh][32][t]
// R14: m-tile 128 (grid 768 blocks), 2 m-frags/wave, acc[2][4], 8 MFMA per 4
// ds_read. W staged in LDS, Q scale folded into W pre-rounding. Epilogue loops
// 2x over the proven 64-row store paths. (Unchanged this round.)
__global__ __launch_bounds__(256) void qkv_proj(
    const float* __restrict__ Aq, const float* __restrict__ Ak, const float* __restrict__ Av,
    const float* __restrict__ Wq, const float* __restrict__ Wk, const float* __restrict__ Wv,
    const float* __restrict__ bq, const float* __restrict__ bk, const float* __restrict__ bv,
    unsigned short* __restrict__ qh, unsigned short* __restrict__ kh, unsigned short* __restrict__ vt) {
  __shared__ __align__(16) unsigned short lds[64 * 256];   // 32 KB: W-tile, then out-stage
  const int z = blockIdx.z;
  const float* A = z == 0 ? Aq : z == 1 ? Ak : Av;
  const float* W = z == 0 ? Wq : z == 1 ? Wk : Wv;
  const float* bias = z == 0 ? bq : z == 1 ? bk : bv;
  const float wscale = z == 0 ? QSCALE * LOG2E : 1.0f;
  const float bscale = z == 0 ? LOG2E : 1.0f;
  const int tid = threadIdx.x;
  const int lane = tid & 63;
  const int wave = tid >> 6;
  const int quad = lane >> 4;
  const int l16 = lane & 15;
  const int m0b = blockIdx.x * 128;
  const int m0 = m0b + wave * 16;
  const int n0 = blockIdx.y * 64;

  stage_w(lds, W, n0, wscale, tid);
  __syncthreads();

  f32x4 acc[2][4];
#pragma unroll
  for (int h = 0; h < 2; ++h)
#pragma unroll
    for (int i = 0; i < 4; ++i) acc[h][i] = f32x4{0.f, 0.f, 0.f, 0.f};
  const float* arow0 = A + (m0 + l16) * EMB;
  const float* arow1 = A + (m0 + 64 + l16) * EMB;
#pragma unroll
  for (int k0 = 0; k0 < EMB; k0 += 32) {
    bf16x8 a0 = pack8(arow0 + k0 + quad * 8);
    bf16x8 a1 = pack8(arow1 + k0 + quad * 8);
#pragma unroll
    for (int nt = 0; nt < 4; ++nt) {
      bf16x8 b = read_w(lds, nt * 16 + l16, k0, quad);
      acc[0][nt] = __builtin_amdgcn_mfma_f32_16x16x32_bf16(a0, b, acc[0][nt], 0, 0, 0);
      acc[1][nt] = __builtin_amdgcn_mfma_f32_16x16x32_bf16(a1, b, acc[1][nt], 0, 0, 0);
    }
  }
  __syncthreads();   // all waves done reading W tile; reuse lds as out-stage (stride 72)

  float bn[4];
#pragma unroll
  for (int nt = 0; nt < 4; ++nt) bn[nt] = bias[n0 + nt * 16 + l16] * bscale;

#pragma unroll
  for (int h = 0; h < 2; ++h) {
#pragma unroll
    for (int nt = 0; nt < 4; ++nt)
#pragma unroll
      for (int r = 0; r < 4; ++r)
        lds[(wave * 16 + quad * 4 + r) * 72 + nt * 16 + l16] = bfr(acc[h][nt][r] + bn[nt]);
    __syncthreads();
    if (z < 2) {
      // coalesced 32B/thread stores to [bh][t][hd]; 16-col chunk stays inside one head
      int row = tid >> 2, seg = tid & 3;
      int m = m0b + h * 64 + row, t = m >> 2, b = m & 3;
      int n = n0 + seg * 16, hh = n >> 5, hd = n & 31;
      unsigned short* dst = (z == 0 ? qh : kh) + (((b << 3) + hh) * T_LEN + t) * HDIM + hd;
      *(bf16x8*)(dst + 0) = *(const bf16x8*)(lds + row * 72 + seg * 16 + 0);
      *(bf16x8*)(dst + 8) = *(const bf16x8*)(lds + row * 72 + seg * 16 + 8);
    } else {
      // transposed [bh][hd][t]: each thread emits one 32B t-contiguous chunk
      int n = tid >> 2, b = tid & 3;
      unsigned w[8];
#pragma unroll
      for (int i = 0; i < 8; ++i) {
        unsigned lo = lds[((2 * i) * 4 + b) * 72 + n];
        unsigned hi = lds[((2 * i + 1) * 4 + b) * 72 + n];
        w[i] = lo | (hi << 16);
      }
      int nf = n0 + n, hh = nf >> 5, hd = nf & 31;
      int tbase = (m0b >> 2) + h * 16;
      unsigned* base = (unsigned*)(vt + (((b << 3) + hh) * HDIM + hd) * T_LEN + tbase);
      ((uint4*)base)[0] = make_uint4(w[0], w[1], w[2], w[3]);
      ((uint4*)base)[1] = make_uint4(w[4], w[5], w[6], w[7]);
    }
    if (h == 0) __syncthreads();   // protect stage buffer before half-1 overwrite
  }
}

// out = A @ W^T + bias ; A bf16 [8192][256], W f32 staged->bf16 LDS, out fp32.
// R15: 512 threads, m-tile 128 (grid 256 blocks = 1/CU, 8 waves = 2/SIMD --
// same waves/SIMD as the old 2x 256-thr blocks, so TLP is held constant while
// stage_w work and W re-fetch per unit output HALVE). One 16-row m-frag per
// wave, acc[4]. f32 out-stage loops two 64-row halves (waves 4h..4h+3 write,
// all 512 threads store).
__global__ __launch_bounds__(512) void out_gemm(const unsigned short* __restrict__ A,
                                                const float* __restrict__ W,
                                                const float* __restrict__ bias,
                                                float* __restrict__ out) {
  __shared__ __align__(16) unsigned short lds[64 * 256];   // 32 KB: W-tile, then f32 out-stage
  const int tid = threadIdx.x;
  const int lane = tid & 63;
  const int wave = tid >> 6;          // 0..7
  const int quad = lane >> 4;
  const int l16 = lane & 15;
  const int m0b = blockIdx.x * 128;
  const int m0 = m0b + wave * 16;
  const int n0 = blockIdx.y * 64;

  stage_w512(lds, W, n0, tid);
  __syncthreads();

  f32x4 acc[4];
#pragma unroll
  for (int i = 0; i < 4; ++i) acc[i] = f32x4{0.f, 0.f, 0.f, 0.f};
  const unsigned short* arow = A + (m0 + l16) * EMB;
#pragma unroll
  for (int k0 = 0; k0 < EMB; k0 += 32) {
    bf16x8 af = *(const bf16x8*)(arow + k0 + quad * 8);
#pragma unroll
    for (int nt = 0; nt < 4; ++nt) {
      bf16x8 b = read_w(lds, nt * 16 + l16, k0, quad);
      acc[nt] = __builtin_amdgcn_mfma_f32_16x16x32_bf16(af, b, acc[nt], 0, 0, 0);
    }
  }

  float bn[4];
#pragma unroll
  for (int nt = 0; nt < 4; ++nt) bn[nt] = bias[n0 + nt * 16 + l16];

  float* fs = (float*)lds;
#pragma unroll
  for (int h = 0; h < 2; ++h) {
    __syncthreads();   // h=0: waves done reading W-tile; h=1: half-0 stores done
    if ((wave >> 2) == h) {
      const int wl = wave & 3;
#pragma unroll
      for (int nt = 0; nt < 4; ++nt)
#pragma unroll
        for (int r = 0; r < 4; ++r)
          fs[(wl * 16 + quad * 4 + r) * 68 + nt * 16 + l16] = acc[nt][r] + bn[nt];
    }
    __syncthreads();
    // store 64 rows x 64 f32: row = tid>>3, seg = tid&7 -> 8 f32 (2x float4)
    const int row = tid >> 3, seg = tid & 7;
    float4 v0 = *(const float4*)(fs + row * 68 + seg * 8);
    float4 v1 = *(const float4*)(fs + row * 68 + seg * 8 + 4);
    float4* dstp = (float4*)(out + (m0b + h * 64 + row) * EMB + n0 + seg * 8);
    dstp[0] = v0;
    dstp[1] = v1;
  }
}

// Flash attention R13: 512 threads / 8 waves per block, ONE q-frag (16 rows)
// per wave. 4 waves/SIMD hide the serial QK->exp2->pack->PV chain. Within ~15%
// of its LDS-read floor (8 waves x 16KB/chunk x 16 chunks @ 256B/clk/CU x 2
// blocks). (Unchanged this round.)
__global__ __launch_bounds__(512) void flash_attn(const unsigned short* __restrict__ qh,
                                                  const unsigned short* __restrict__ kh,
                                                  const unsigned short* __restrict__ vt,
                                                  unsigned short* __restrict__ aout) {
  __shared__ __align__(16) unsigned short kbuf[2][128 * 32];      // 2 x 8 KB, flat copy of K rows
  __shared__ __align__(16) unsigned short vbuf[2][32 * 136];      // 2 x 8.5 KB, V [d][key], stride 136
  const int tid = threadIdx.x;
  const int lane = tid & 63;
  const int wave = tid >> 6;          // 0..7
  const int quad = lane >> 4;
  const int l16 = lane & 15;
  const int bh = blockIdx.x;
  const int q0 = blockIdx.y * 128 + wave * 16;
  const unsigned short* qs = qh + bh * (T_LEN * HDIM);
  const unsigned short* ks = kh + bh * (T_LEN * HDIM);
  const unsigned short* vs = vt + bh * (T_LEN * HDIM);
  const bf16x8 qf = *(const bf16x8*)(qs + (q0 + l16) * HDIM + quad * 8);
  f32x4 o0 = {0.f, 0.f, 0.f, 0.f};
  f32x4 o1 = o0;
  float den = 0.f;
  const f32x4 zero = o0;

  // staging split across 512 threads: K one uint4/thread (128 rows x 32),
  // V one uint4/thread (32 d-rows x 128 keys)
  const int vrow = tid >> 4;          // 0..31
  const int vcol = (tid & 15) * 8;    // 16B units along keys

  // stage chunk 0
  {
    uint4 ka = *(const uint4*)(ks + tid * 8);
    uint4 va = *(const uint4*)(vs + vrow * T_LEN + vcol);
    *(uint4*)(&kbuf[0][tid * 8]) = ka;
    *(uint4*)(&vbuf[0][vrow * 136 + vcol]) = va;
  }
  __syncthreads();

  for (int chunk = 0; chunk < 16; ++chunk) {
    const int buf = chunk & 1;
    uint4 ka, va;
    const bool pf = (chunk + 1) < 16;
    if (pf) {
      const int kk0 = (chunk + 1) * 128;
      ka = *(const uint4*)(ks + kk0 * HDIM + tid * 8);
      va = *(const uint4*)(vs + vrow * T_LEN + kk0 + vcol);
    }
#pragma unroll
    for (int it = 0; it < 8; ++it) {
      const int kkl = it * 16;
      bf16x8 kf = *(const bf16x8*)(&kbuf[buf][(kkl + l16) * 32 + quad * 8]);
      bf16x4 vfa = *(const bf16x4*)(&vbuf[buf][l16 * 136 + kkl + quad * 4]);
      bf16x4 vfb = *(const bf16x4*)(&vbuf[buf][(l16 + 16) * 136 + kkl + quad * 4]);
      __builtin_amdgcn_s_setprio(1);
      f32x4 s = __builtin_amdgcn_mfma_f32_16x16x32_bf16(kf, qf, zero, 0, 0, 0);
      __builtin_amdgcn_s_setprio(0);
      union { unsigned u[2]; bf16x4 v; } pp;
      {
        float a = __builtin_amdgcn_exp2f(s[0]), b = __builtin_amdgcn_exp2f(s[1]);
        float c = __builtin_amdgcn_exp2f(s[2]), d = __builtin_amdgcn_exp2f(s[3]);
        pp.u[0] = pack2r(a, b); pp.u[1] = pack2r(c, d);
        den += (a + b) + (c + d);
      }
      __builtin_amdgcn_s_setprio(1);
      o0 = __builtin_amdgcn_mfma_f32_16x16x16bf16_1k(vfa, pp.v, o0, 0, 0, 0);
      o1 = __builtin_amdgcn_mfma_f32_16x16x16bf16_1k(vfb, pp.v, o1, 0, 0, 0);
      __builtin_amdgcn_s_setprio(0);
    }
    if (pf) {
      const int nb = buf ^ 1;
      *(uint4*)(&kbuf[nb][tid * 8]) = ka;
      *(uint4*)(&vbuf[nb][vrow * 136 + vcol]) = va;
    }
    __syncthreads();
  }

  // denominator: per-lane partial covers k = quad*4+{0..3} slices; full sum for
  // q=l16 is the reduction over the 4 quads (lane bits 4,5)
  float d0 = den; d0 += __shfl_xor(d0, 16); d0 += __shfl_xor(d0, 32);

  // epilogue: normalize + O^T (C-layout: d=quad*4+r, q=l16) -> row-major [q][d]
  const int srcA = l16 + ((quad & 1) << 5);
  const int srcB = srcA + 16;
  const bool lowq = quad < 2;
  const int b = bh >> 3, h = bh & 7;
  {
    const float inv = 1.f / d0;
    unsigned oa = pack2r(o0[0] * inv, o0[1] * inv), ob = pack2r(o0[2] * inv, o0[3] * inv);
    unsigned oc = pack2r(o1[0] * inv, o1[1] * inv), od = pack2r(o1[2] * inv, o1[3] * inv);
    union { unsigned u[4]; bf16x8 v; } of;
    unsigned ta, tc;
    ta = __shfl(oa, srcA); tc = __shfl(oc, srcA); of.u[0] = lowq ? ta : tc;
    ta = __shfl(ob, srcA); tc = __shfl(od, srcA); of.u[1] = lowq ? ta : tc;
    ta = __shfl(oa, srcB); tc = __shfl(oc, srcB); of.u[2] = lowq ? ta : tc;
    ta = __shfl(ob, srcB); tc = __shfl(od, srcB); of.u[3] = lowq ? ta : tc;
    const int t = q0 + l16;
    *(bf16x8*)(aout + (t * BSZ + b) * EMB + h * HDIM + quad * 8) = of.v;
  }
}

extern "C" void kernel_launch(void* const* d_in, const int* in_sizes, int n_in,
                              void* d_out, int out_size, void* d_ws, size_t ws_size,
                              hipStream_t stream) {
  const float* q  = (const float*)d_in[0];
  const float* k  = (const float*)d_in[1];
  const float* v  = (const float*)d_in[2];
  const float* Wq = (const float*)d_in[3];
  const float* bq = (const float*)d_in[4];
  const float* Wk = (const float*)d_in[5];
  const float* bk = (const float*)d_in[6];
  const float* Wv = (const float*)d_in[7];
  const float* bv = (const float*)d_in[8];
  const float* Wp = (const float*)d_in[9];
  const float* bp = (const float*)d_in[10];
  float* out = (float*)d_out;

  char* ws = (char*)d_ws;
  unsigned short* qh   = (unsigned short*)(ws);                    // 4 MiB
  unsigned short* kh   = (unsigned short*)(ws + (4u << 20));       // 4 MiB
  unsigned short* vt   = (unsigned short*)(ws + (8u << 20));       // 4 MiB
  unsigned short* aout = (unsigned short*)(ws + (12u << 20));      // 4 MiB

  qkv_proj<<<dim3(64, 4, 3), 256, 0, stream>>>(q, k, v, Wq, Wk, Wv, bq, bk, bv, qh, kh, vt);
  flash_attn<<<dim3(32, 16), 512, 0, stream>>>(qh, kh, vt, aout);
  out_gemm<<<dim3(64, 4), 512, 0, stream>>>(aout, Wp, bp, out);
}